// Round 2
// baseline (393.366 us; speedup 1.0000x reference)
//
#include <hip/hip_runtime.h>
#include <hip/hip_bf16.h>
#include <math.h>

// Problem constants (FavorPlusAttention): B=2, T=4096, d=1024, h=16, dk=64, m=256
#define BB 2
#define TT 4096
#define DD 1024
#define NH 16
#define DK 64
#define MM 256
#define BT (BB*TT)        // 8192 rows
#define FEPS 1e-6f

typedef _Float16 f16x8 __attribute__((ext_vector_type(8)));
using f32x4 = __attribute__((ext_vector_type(4))) float;

#define GL2LDS16(g, l) __builtin_amdgcn_global_load_lds( \
    (const __attribute__((address_space(1))) void*)(g), \
    (__attribute__((address_space(3))) void*)(l), 16, 0, 0)

static __device__ __forceinline__ unsigned short f16bits(_Float16 v) {
    union { _Float16 f; unsigned short u; } c; c.f = v; return c.u;
}

// ---------------------------------------------------------------------------
// hi/lo fp16 split: src [rows][1024] fp32 -> dst [rows][2048] f16 = [hi|lo]
// ---------------------------------------------------------------------------
__global__ __launch_bounds__(256) void split_hl(const float* __restrict__ src,
                                                unsigned short* __restrict__ dst)
{
    const int r = blockIdx.x;
    const int c = threadIdx.x * 4;
    float4 v = *(const float4*)(src + (size_t)r * 1024 + c);
    float f[4] = {v.x, v.y, v.z, v.w};
    union { _Float16 h[4]; uint2 u; } hv, lv;
#pragma unroll
    for (int i = 0; i < 4; i++) {
        hv.h[i] = (_Float16)f[i];
        lv.h[i] = (_Float16)(f[i] - (float)hv.h[i]);
    }
    unsigned short* d = dst + (size_t)r * 2048;
    *(uint2*)(d + c)        = hv.u;
    *(uint2*)(d + 1024 + c) = lv.u;
}

// hi-only fp16 weight cast: 3 weights -> [3][1024][1024] f16 (B-operand).
__global__ __launch_bounds__(256) void split_w3h(const float* __restrict__ W0,
                                                 const float* __restrict__ W1,
                                                 const float* __restrict__ W2,
                                                 unsigned short* __restrict__ dst)
{
    const int r = blockIdx.x;            // 0..3071
    const int wi = r >> 10, rr = r & 1023;
    const float* W = (wi == 0) ? W0 : (wi == 1) ? W1 : W2;
    const int c = threadIdx.x * 4;
    float4 v = *(const float4*)(W + (size_t)rr * 1024 + c);
    float f[4] = {v.x, v.y, v.z, v.w};
    union { _Float16 h[4]; uint2 u; } hv;
#pragma unroll
    for (int i = 0; i < 4; i++) hv.h[i] = (_Float16)f[i];
    *(uint2*)(dst + (size_t)r * 1024 + c) = hv.u;
}

// ---------------------------------------------------------------------------
// gemm_hl: hi/lo-fused split-fp16 GEMM. C = scale*((A_hi+A_lo)@B_hi^T)(+bias).
// A: [8192][2048] f16 [hi|lo planes], B: [1024][1024] f16 hi. Real K = 1024,
// BK=32, 32 K-tiles. BM=128, BN=256, 4 waves (2Mx2N), wave tile 64x128
// (mf=4 x nf=8 of 16x16x32 f16 MFMA), acc[4][8] f32x4 = 128 VGPR.
// LDS 64 KB (2 blocks/CU): per buf 32 KB = Ah[8K] | Al[8K] | B[16K],
// CHUNK-MAJOR layout: chunk s=(kc*ROWS+row) at byte s*16 -> both gl2lds
// writes (lane-linear) and frag ds_read_b128 (bank=(row*4)%32) are at the
// hardware-minimum 2-lanes/bank; no swizzle needed.
// Schedule (verified 2-phase counted-vmcnt skeleton):
//  P0: stage A(t+1) hi+lo [4 gl2lds]; read ah[4],b[8]; bar; lgkm0; prio1;
//      32 MFMA (hi); prio0; bar.
//  P1: stage B(t+2) [4 gl2lds]; read al[4]; vmcnt(4); bar; lgkm0; prio1;
//      32 MFMA (lo, b reused in regs); prio0; bar.
// Per-thread queue: enter tile t with B(t+1)[4] outstanding; P0 +A(t+1)[4];
// P1 +B(t+2)[4]; vmcnt(4) -> exactly tile t+1 landed. Every gl2lds issue is
// >=1 barrier after the last lgkm-completed ds_read of its dest region.
// ---------------------------------------------------------------------------
__global__ __launch_bounds__(256, 2) void gemm_hl(
    const unsigned short* __restrict__ A,
    const unsigned short* __restrict__ B0, const unsigned short* __restrict__ B1,
    const unsigned short* __restrict__ B2,
    float* __restrict__ C0, float* __restrict__ C1, float* __restrict__ C2,
    const float* __restrict__ bias,
    float sc0, float sc1, float sc2)
{
    extern __shared__ char smem[];   // 65536 B: buf*32768 + {Ah 0, Al 8192, B 16384}

    const int which = blockIdx.x >> 2;
    const int col0 = (blockIdx.x & 3) * 256;
    const int row0 = blockIdx.y * 128;
    const unsigned short* Bp = (which == 0) ? B0 : (which == 1) ? B1 : B2;
    float* Cp = (which == 0) ? C0 : (which == 1) ? C1 : C2;
    const float scl = (which == 0) ? sc0 : (which == 1) ? sc1 : sc2;

    const int tid = threadIdx.x;             // 0..255
    const int w = tid >> 6, lane = tid & 63;
    const int wm = w >> 1, wn = w & 1;       // 2M x 2N wave grid

    // ---- staging: chunk s = kc*ROWS + row; lane l of load i covers
    // s = i*256 + w*64 + l = tid + i*256; LDS dest byte = s*16 (lane-linear).
    const int sA0 = tid, sA1 = tid + 256;                    // A: 512 chunks (4kc x 128row)
    const unsigned short* aS0 = A + (size_t)(row0 + (sA0 & 127)) * 2048 + (sA0 >> 7) * 8;
    const unsigned short* aS1 = A + (size_t)(row0 + (sA1 & 127)) * 2048 + (sA1 >> 7) * 8;
    const unsigned short* bS0 = Bp + (size_t)(col0 + (tid & 255)) * 1024 + 0 * 8;          // i=0: s=tid
    const unsigned short* bS1 = Bp + (size_t)(col0 + ((tid + 256) & 255)) * 1024 + ((tid + 256) >> 8) * 8;
    const unsigned short* bS2 = Bp + (size_t)(col0 + ((tid + 512) & 255)) * 1024 + ((tid + 512) >> 8) * 8;
    const unsigned short* bS3 = Bp + (size_t)(col0 + ((tid + 768) & 255)) * 1024 + ((tid + 768) >> 8) * 8;
    const int dW0 = (w * 64) * 16;                           // wave-uniform dest bases
    const int dW1 = (256 + w * 64) * 16;
    const int dW2 = (512 + w * 64) * 16;
    const int dW3 = (768 + w * 64) * 16;

    auto stA = [&](int buf, int kt) {         // A hi+lo: 4 gl2lds/thread
        char* base = smem + buf * 32768;
        const int kh = kt * 32;
        GL2LDS16(aS0 + kh, base + dW0);
        GL2LDS16(aS1 + kh, base + dW1);
        GL2LDS16(aS0 + 1024 + kh, base + 8192 + dW0);
        GL2LDS16(aS1 + 1024 + kh, base + 8192 + dW1);
    };
    auto stB = [&](int buf, int kt) {         // B: 4 gl2lds/thread
        char* base = smem + buf * 32768 + 16384;
        const int kb = kt * 32;
        GL2LDS16(bS0 + kb, base + dW0);
        GL2LDS16(bS1 + kb, base + dW1);
        GL2LDS16(bS2 + kb, base + dW2);
        GL2LDS16(bS3 + kb, base + dW3);
    };

    // ---- frag read byte offsets (chunk-major; +mf*256 / +nf*256 walks rows)
    const int aRd = (lane >> 4) * 2048 + wm * 1024 + (lane & 15) * 16;
    const int bRd = 16384 + (lane >> 4) * 4096 + wn * 2048 + (lane & 15) * 16;

    f32x4 acc[4][8];
#pragma unroll
    for (int i = 0; i < 4; i++)
#pragma unroll
        for (int j = 0; j < 8; j++) acc[i][j] = (f32x4){0.f, 0.f, 0.f, 0.f};
    f16x8 ah[4], al[4], bf[8];

    // ---- prologue: queue = B(0)[4], A(0)[4], B(1)[4]; vmcnt(4) -> tile 0 in
    stB(0, 0);
    stA(0, 0);
    stB(1, 1);
    asm volatile("s_waitcnt vmcnt(4)" ::: "memory");
    __builtin_amdgcn_s_barrier();

#pragma unroll 2
    for (int t = 0; t < 32; ++t) {
        const int buf = t & 1;
        const int ab = buf * 32768;
        // ============ phase 0: stage A(t+1); read ah+b; hi MFMAs
        stA(buf ^ 1, (t + 1 < 32) ? t + 1 : 0);
#pragma unroll
        for (int mf = 0; mf < 4; ++mf)
            ah[mf] = *(const f16x8*)(smem + ab + aRd + mf * 256);
#pragma unroll
        for (int nf = 0; nf < 8; ++nf)
            bf[nf] = *(const f16x8*)(smem + ab + bRd + nf * 256);
        __builtin_amdgcn_s_barrier();
        asm volatile("s_waitcnt lgkmcnt(0)" ::: "memory");
        __builtin_amdgcn_sched_barrier(0);
        __builtin_amdgcn_s_setprio(1);
#pragma unroll
        for (int mf = 0; mf < 4; ++mf)
#pragma unroll
            for (int nf = 0; nf < 8; ++nf)
                acc[mf][nf] = __builtin_amdgcn_mfma_f32_16x16x32_f16(
                    ah[mf], bf[nf], acc[mf][nf], 0, 0, 0);
        __builtin_amdgcn_s_setprio(0);
        __builtin_amdgcn_s_barrier();
        // ============ phase 1: stage B(t+2); read al; vmcnt; lo MFMAs
        stB(buf, (t + 2 < 32) ? t + 2 : 0);
#pragma unroll
        for (int mf = 0; mf < 4; ++mf)
            al[mf] = *(const f16x8*)(smem + ab + 8192 + aRd + mf * 256);
        asm volatile("s_waitcnt vmcnt(4)" ::: "memory");
        __builtin_amdgcn_s_barrier();
        asm volatile("s_waitcnt lgkmcnt(0)" ::: "memory");
        __builtin_amdgcn_sched_barrier(0);
        __builtin_amdgcn_s_setprio(1);
#pragma unroll
        for (int mf = 0; mf < 4; ++mf)
#pragma unroll
            for (int nf = 0; nf < 8; ++nf)
                acc[mf][nf] = __builtin_amdgcn_mfma_f32_16x16x32_f16(
                    al[mf], bf[nf], acc[mf][nf], 0, 0, 0);
        __builtin_amdgcn_s_setprio(0);
        __builtin_amdgcn_s_barrier();
    }
    asm volatile("s_waitcnt vmcnt(0)" ::: "memory");   // drain tail junk loads

    // ---- epilogue: C/D layout col = lane&15, row = (lane>>4)*4 + reg  [m89]
    float bv[8];
#pragma unroll
    for (int nf = 0; nf < 8; ++nf) {
        int gcol = col0 + wn * 128 + nf * 16 + (lane & 15);
        bv[nf] = bias ? bias[gcol] : 0.f;
    }
#pragma unroll
    for (int mf = 0; mf < 4; ++mf) {
        const int grow = row0 + wm * 64 + mf * 16 + (lane >> 4) * 4;
#pragma unroll
        for (int r = 0; r < 4; ++r) {
            float* Crow = Cp + (size_t)(grow + r) * 1024;
#pragma unroll
            for (int nf = 0; nf < 8; ++nf) {
                int gcol = col0 + wn * 128 + nf * 16 + (lane & 15);
                Crow[gcol] = acc[mf][nf][r] * scl + bv[nf];
            }
        }
    }
}

// ---------------------------------------------------------------------------
// FAVOR+ features via MFMA (phiK only): per block one bh, [128 t x 256 m].
// Unchanged (verified).
// ---------------------------------------------------------------------------
__global__ __launch_bounds__(256) void favor_mfma(const float* __restrict__ X,
                                                  const float* __restrict__ proj,
                                                  float* __restrict__ phi)
{
    const int bh = blockIdx.y;
    const int b = bh >> 4, h = bh & 15;
    const int t0 = blockIdx.x * 128;
    const int tid = threadIdx.x;
    const int w = tid >> 6, lane = tid & 63;

    __shared__ unsigned short Aq[128 * 136];   // [t][k'], hi 0..63, lo 64..127
    __shared__ unsigned short Bs[256 * 72];    // [m][k] hi only
    __shared__ float xns[128];

    const float* Xb = X + ((size_t)b * TT + t0) * DD + h * DK;
    const float* Pj = proj + (size_t)h * MM * DK;

#pragma unroll
    for (int i = 0; i < 8; i++) {
        int s = tid + i * 256;
        int r = s >> 4, q = (s & 15) * 4;
        float4 v = *(const float4*)(Xb + (size_t)r * DD + q);
        float f[4] = {v.x, v.y, v.z, v.w};
        union { _Float16 h[4]; uint2 u; } hv, lv;
#pragma unroll
        for (int e = 0; e < 4; e++) {
            hv.h[e] = (_Float16)f[e];
            lv.h[e] = (_Float16)(f[e] - (float)hv.h[e]);
        }
        *(uint2*)&Aq[r * 136 + q]      = hv.u;
        *(uint2*)&Aq[r * 136 + 64 + q] = lv.u;
    }
#pragma unroll
    for (int i = 0; i < 16; i++) {
        int s = tid + i * 256;
        int r = s >> 4, q = (s & 15) * 4;
        float4 v = *(const float4*)(Pj + (size_t)r * DK + q);
        float f[4] = {v.x, v.y, v.z, v.w};
        union { _Float16 h[4]; uint2 u; } hv;
#pragma unroll
        for (int e = 0; e < 4; e++) hv.h[e] = (_Float16)f[e];
        *(uint2*)&Bs[r * 72 + q] = hv.u;
    }
    __syncthreads();

    if (tid < 128) {
        const unsigned short* ar = &Aq[tid * 136];
        float s = 0.f;
#pragma unroll 8
        for (int k = 0; k < 64; k++) {
            float qv = (float)(*(const _Float16*)&ar[k])
                     + (float)(*(const _Float16*)&ar[64 + k]);
            s += qv * qv;
        }
        xns[tid] = s;
    }

    f32x4 acc[2][16];
#pragma unroll
    for (int i = 0; i < 2; i++)
#pragma unroll
        for (int j = 0; j < 16; j++) acc[i][j] = (f32x4){0.f, 0.f, 0.f, 0.f};

    const int arow0 = (w * 32 + (lane & 15)) * 136 + (lane >> 4) * 8;
    const int brow0 = (lane & 15) * 72 + (lane >> 4) * 8;
#pragma unroll
    for (int ks = 0; ks < 4; ks++) {
        f16x8 a0 = *(const f16x8*)&Aq[arow0 + ks * 32];
        f16x8 a1 = *(const f16x8*)&Aq[arow0 + 16 * 136 + ks * 32];
        const int bko = (ks & 1) * 32;
#pragma unroll
        for (int j = 0; j < 16; j++) {
            f16x8 bf = *(const f16x8*)&Bs[brow0 + j * 16 * 72 + bko];
            acc[0][j] = __builtin_amdgcn_mfma_f32_16x16x32_f16(a0, bf, acc[0][j], 0, 0, 0);
            acc[1][j] = __builtin_amdgcn_mfma_f32_16x16x32_f16(a1, bf, acc[1][j], 0, 0, 0);
        }
    }
    __syncthreads();

    float* outp = phi + ((size_t)bh * TT + t0) * MM;
#pragma unroll
    for (int i = 0; i < 2; i++) {
#pragma unroll
        for (int r = 0; r < 4; r++) {
            float mx = acc[i][0][r];
#pragma unroll
            for (int j = 1; j < 16; j++) mx = fmaxf(mx, acc[i][j][r]);
            mx = fmaxf(mx, __shfl_xor(mx, 1, 64));
            mx = fmaxf(mx, __shfl_xor(mx, 2, 64));
            mx = fmaxf(mx, __shfl_xor(mx, 4, 64));
            mx = fmaxf(mx, __shfl_xor(mx, 8, 64));
            const int row = w * 32 + i * 16 + (lane >> 4) * 4 + r;
            const float base = -mx - 0.5f * xns[row];
            float* orow = outp + (size_t)row * MM + (lane & 15);
#pragma unroll
            for (int j = 0; j < 16; j++)
                orow[j * 16] = (__expf(acc[i][j][r] + base) + FEPS) * 0.0625f;
        }
    }
}

// ---------------------------------------------------------------------------
// KV partial tiled GEMM: per block [64 m x 64 dk] over a 512-long t-chunk.
// (unchanged)
// ---------------------------------------------------------------------------
__global__ __launch_bounds__(256) void kv_partial(const float* __restrict__ phiK,
                                                  const float* __restrict__ V,
                                                  float* __restrict__ KVp)
{
    const int bh = blockIdx.y;
    const int b = bh >> 4, h = bh & 15;
    const int mt = blockIdx.x & 3;          // m-tile (64 wide)
    const int split = blockIdx.x >> 2;      // 0..7, 512 t each
    const int m0 = mt * 64;
    const int tid = threadIdx.x;
    const int tx = tid & 15;    // dk, 4 each
    const int ty = tid >> 4;    // m, 4 each

    __shared__ float Ps[32][68];
    __shared__ float Vs[32][68];

    float acc[4][4];
#pragma unroll
    for (int i = 0; i < 4; i++)
#pragma unroll
        for (int j = 0; j < 4; j++) acc[i][j] = 0.f;
    float ks0 = 0.f, ks1 = 0.f, ks2 = 0.f, ks3 = 0.f;

    const size_t pbase = (size_t)bh * TT * MM + m0;
    const size_t vbase = (size_t)b * TT * DD + h * DK;

    const int lt = tid >> 3;
    const int lc = (tid & 7) * 8;

    const int tend = split * 512 + 512;
    for (int t0 = split * 512; t0 < tend; t0 += 32) {
        const float* prow = phiK + pbase + (size_t)(t0 + lt) * MM + lc;
        const float* vrow = V + vbase + (size_t)(t0 + lt) * DD + lc;
        float4 p0 = *(const float4*)(prow);
        float4 p1 = *(const float4*)(prow + 4);
        float4 v0 = *(const float4*)(vrow);
        float4 v1 = *(const float4*)(vrow + 4);
        *(float4*)&Ps[lt][lc]     = p0;
        *(float4*)&Ps[lt][lc + 4] = p1;
        *(float4*)&Vs[lt][lc]     = v0;
        *(float4*)&Vs[lt][lc + 4] = v1;
        __syncthreads();
#pragma unroll
        for (int k = 0; k < 32; k++) {
            float4 a4 = *(const float4*)&Ps[k][ty * 4];
            float4 b4 = *(const float4*)&Vs[k][tx * 4];
            ks0 += a4.x; ks1 += a4.y; ks2 += a4.z; ks3 += a4.w;
            acc[0][0] += a4.x * b4.x; acc[0][1] += a4.x * b4.y;
            acc[0][2] += a4.x * b4.z; acc[0][3] += a4.x * b4.w;
            acc[1][0] += a4.y * b4.x; acc[1][1] += a4.y * b4.y;
            acc[1][2] += a4.y * b4.z; acc[1][3] += a4.y * b4.w;
            acc[2][0] += a4.z * b4.x; acc[2][1] += a4.z * b4.y;
            acc[2][2] += a4.z * b4.z; acc[2][3] += a4.z * b4.w;
            acc[3][0] += a4.w * b4.x; acc[3][1] += a4.w * b4.y;
            acc[3][2] += a4.w * b4.z; acc[3][3] += a4.w * b4.w;
        }
        __syncthreads();
    }

    float ksv[4] = {ks0, ks1, ks2, ks3};
    float* o = KVp + (((size_t)split * 32 + bh) * MM + m0) * 68;
#pragma unroll
    for (int i = 0; i < 4; i++) {
        float* orow = o + (size_t)(ty * 4 + i) * 68 + tx * 4;
        orow[0] = acc[i][0]; orow[1] = acc[i][1];
        orow[2] = acc[i][2]; orow[3] = acc[i][3];
        if (tx == 0) o[(size_t)(ty * 4 + i) * 68 + 64] = ksv[i];
    }
}

// ---------------------------------------------------------------------------
// kv_reduce v2: sum 8 split partials and emit KV^T directly as fp16 hi/lo
// planes: KVt16[bh][plane(2)][c(68)][m(256)], c: 0..63 = dk, 64 = Ksum.
// ---------------------------------------------------------------------------
__global__ __launch_bounds__(256) void kv_reduce(const float* __restrict__ KVp,
                                                 unsigned short* __restrict__ KVt16)
{
    int idx = blockIdx.x * 256 + threadIdx.x;   // 32*256*68 = 557056 exact
    float s = 0.f;
    for (int sp = 0; sp < 8; sp++) s += KVp[(size_t)sp * 32 * MM * 68 + idx];
    int bh = idx / 17408;
    int rm = idx - bh * 17408;
    int m = rm / 68;
    int c = rm - m * 68;
    _Float16 hv = (_Float16)0.f, lv = (_Float16)0.f;
    if (c <= 64) {
        hv = (_Float16)s;
        lv = (_Float16)(s - (float)hv);
    }
    KVt16[((size_t)(bh * 2 + 0) * 68 + c) * 256 + m] = f16bits(hv);
    KVt16[((size_t)(bh * 2 + 1) * 68 + c) * 256 + m] = f16bits(lv);
}

// ---------------------------------------------------------------------------
// FUSED favor(Q) + attn_out: per block one bh, 128 t rows. (unchanged)
// ---------------------------------------------------------------------------
__global__ __launch_bounds__(256, 2) void favor_attn(
    const float* __restrict__ X,
    const float* __restrict__ proj,
    const unsigned short* __restrict__ KVt16,
    unsigned short* __restrict__ mout)
{
    extern __shared__ char smem[];
    unsigned short* Xq = (unsigned short*)smem;             // [128][136]
    unsigned short* Pp = (unsigned short*)(smem + 34816);   // [256][72]
    float* xns         = (float*)(smem + 71680);            // [128]
    unsigned short* Aq = Xq;                                // phase B alias
    unsigned short* Bt = Pp;                                // [80][136]

    const int bh = blockIdx.y;
    const int b = bh >> 4, h = bh & 15;
    const int t0 = blockIdx.x * 128;
    const int tid = threadIdx.x;
    const int w = tid >> 6, lane = tid & 63;

    const float* Xb = X + ((size_t)b * TT + t0) * DD + h * DK;
    const float* Pj = proj + (size_t)h * MM * DK;

    // ---- phase A: stage X (hi/lo) + proj (hi) ----
#pragma unroll
    for (int i = 0; i < 8; i++) {
        int s = tid + i * 256;
        int r = s >> 4, q = (s & 15) * 4;
        float4 v = *(const float4*)(Xb + (size_t)r * DD + q);
        float f[4] = {v.x, v.y, v.z, v.w};
        union { _Float16 h[4]; uint2 u; } hv, lv;
#pragma unroll
        for (int e = 0; e < 4; e++) {
            hv.h[e] = (_Float16)f[e];
            lv.h[e] = (_Float16)(f[e] - (float)hv.h[e]);
        }
        *(uint2*)&Xq[r * 136 + q]      = hv.u;
        *(uint2*)&Xq[r * 136 + 64 + q] = lv.u;
    }
#pragma unroll
    for (int i = 0; i < 16; i++) {
        int s = tid + i * 256;
        int r = s >> 4, q = (s & 15) * 4;
        float4 v = *(const float4*)(Pj + (size_t)r * DK + q);
        float f[4] = {v.x, v.y, v.z, v.w};
        union { _Float16 h[4]; uint2 u; } hv;
#pragma unroll
        for (int e = 0; e < 4; e++) hv.h[e] = (_Float16)f[e];
        *(uint2*)&Pp[r * 72 + q] = hv.u;
    }
    __syncthreads();

    if (tid < 128) {
        const unsigned short* ar = &Xq[tid * 136];
        float s = 0.f;
#pragma unroll 8
        for (int k = 0; k < 64; k++) {
            float qv = (float)(*(const _Float16*)&ar[k])
                     + (float)(*(const _Float16*)&ar[64 + k]);
            s += qv * qv;
        }
        xns[tid] = s;
    }

    f32x4 facc[2][16];
#pragma unroll
    for (int i = 0; i < 2; i++)
#pragma unroll
        for (int j = 0; j < 16; j++) facc[i][j] = (f32x4){0.f, 0.f, 0.f, 0.f};

    const int arow0 = (w * 32 + (lane & 15)) * 136 + (lane >> 4) * 8;
    const int brow0 = (lane & 15) * 72 + (lane >> 4) * 8;
#pragma unroll
    for (int ks = 0; ks < 4; ks++) {
        f16x8 a0 = *(const f16x8*)&Xq[arow0 + ks * 32];
        f16x8 a1 = *(const f16x8*)&Xq[arow0 + 16 * 136 + ks * 32];
        const int bko = (ks & 1) * 32;
#pragma unroll
        for (int j = 0; j < 16; j++) {
            f16x8 bf = *(const f16x8*)&Pp[brow0 + j * 16 * 72 + bko];
            facc[0][j] = __builtin_amdgcn_mfma_f32_16x16x32_f16(a0, bf, facc[0][j], 0, 0, 0);
            facc[1][j] = __builtin_amdgcn_mfma_f32_16x16x32_f16(a1, bf, facc[1][j], 0, 0, 0);
        }
    }
    __syncthreads();   // phase A LDS reads done; xns visible

    // rowmax -> base per (i, r)
    float base[2][4];
#pragma unroll
    for (int i = 0; i < 2; i++) {
#pragma unroll
        for (int r = 0; r < 4; r++) {
            float mx = facc[i][0][r];
#pragma unroll
            for (int j = 1; j < 16; j++) mx = fmaxf(mx, facc[i][j][r]);
            mx = fmaxf(mx, __shfl_xor(mx, 1, 64));
            mx = fmaxf(mx, __shfl_xor(mx, 2, 64));
            mx = fmaxf(mx, __shfl_xor(mx, 4, 64));
            mx = fmaxf(mx, __shfl_xor(mx, 8, 64));
            const int row = w * 32 + i * 16 + (lane >> 4) * 4 + r;
            base[i][r] = -mx - 0.5f * xns[row];
        }
    }

    // ---- phase B: chunked phi->Aq + KV^T->Bt + 3-seg MFMA ----
    f32x4 aacc[2][5];
#pragma unroll
    for (int i = 0; i < 2; i++)
#pragma unroll
        for (int j = 0; j < 5; j++) aacc[i][j] = (f32x4){0.f, 0.f, 0.f, 0.f};

    const int aFr = (w * 32 + (lane & 15)) * 136 + (lane >> 4) * 8;
    const int bFr = (lane & 15) * 136 + (lane >> 4) * 8;

#pragma unroll
    for (int c = 0; c < 4; c++) {
        // write phi chunk (hi|lo) to Aq in A-layout [t][mc]
#pragma unroll
        for (int i = 0; i < 2; i++) {
#pragma unroll
            for (int jj = 0; jj < 4; jj++) {
#pragma unroll
                for (int r = 0; r < 4; r++) {
                    float ph = (__expf(facc[i][c * 4 + jj][r] + base[i][r]) + FEPS) * 0.0625f;
                    _Float16 hv = (_Float16)ph;
                    _Float16 lv = (_Float16)(ph - (float)hv);
                    int row = w * 32 + i * 16 + (lane >> 4) * 4 + r;
                    int mc = jj * 16 + (lane & 15);
                    Aq[row * 136 + mc]      = f16bits(hv);
                    Aq[row * 136 + 64 + mc] = f16bits(lv);
                }
            }
        }
        // stage Bt chunk: rows 0..67 from KVt16, 68..79 zero
#pragma unroll
        for (int i = 0; i < 10; i++) {
            int s = tid + i * 256;           // 2560 = 2 planes * 80 rows * 16 quads
            int p = (s >= 1280) ? 1 : 0;
            int s2 = s - p * 1280;
            int r = s2 >> 4, q = (s2 & 15) * 4;
            uint2 v = make_uint2(0u, 0u);
            if (r < 68)
                v = *(const uint2*)(KVt16 + ((size_t)(bh * 2 + p) * 68 + r) * 256 + c * 64 + q);
            *(uint2*)&Bt[r * 136 + p * 64 + q] = v;
        }
        __syncthreads();
#pragma unroll
        for (int ks = 0; ks < 2; ks++) {
            f16x8 ah0 = *(const f16x8*)&Aq[aFr + ks * 32];
            f16x8 ah1 = *(const f16x8*)&Aq[aFr + 16 * 136 + ks * 32];
            f16x8 al0 = *(const f16x8*)&Aq[aFr + 64 + ks * 32];
            f16x8 al1 = *(const f16x8*)&Aq[aFr + 16 * 136 + 64 + ks * 32];
#pragma unroll
            for (int j = 0; j < 5; j++) {
                f16x8 bh_ = *(const f16x8*)&Bt[bFr + j * 16 * 136 + ks * 32];
                f16x8 bl_ = *(const f16x8*)&Bt[bFr + j * 16 * 136 + 64 + ks * 32];
                aacc[0][j] = __builtin_amdgcn_mfma_f32_16x16x32_f16(ah0, bl_, aacc[0][j], 0, 0, 0);
                aacc[0][j] = __builtin_amdgcn_mfma_f32_16x16x32_f16(al0, bh_, aacc[0][j], 0, 0, 0);
                aacc[0][j] = __builtin_amdgcn_mfma_f32_16x16x32_f16(ah0, bh_, aacc[0][j], 0, 0, 0);
                aacc[1][j] = __builtin_amdgcn_mfma_f32_16x16x32_f16(ah1, bl_, aacc[1][j], 0, 0, 0);
                aacc[1][j] = __builtin_amdgcn_mfma_f32_16x16x32_f16(al1, bh_, aacc[1][j], 0, 0, 0);
                aacc[1][j] = __builtin_amdgcn_mfma_f32_16x16x32_f16(ah1, bh_, aacc[1][j], 0, 0, 0);
            }
        }
        __syncthreads();
    }

    // ---- epilogue: out = num/(den+eps), write merged fp16 hi/lo ----
    unsigned short* Mh = mout + ((size_t)b * TT + t0) * 2048 + h * DK;
#pragma unroll
    for (int i = 0; i < 2; i++) {
#pragma unroll
        for (int r = 0; r < 4; r++) {
            float den = aacc[i][4][r];                 // col 64 lives at lane&15==0
            den = __shfl(den, lane & 48, 64);          // broadcast to the 16-lane group
            float dinv = 1.f / (den + FEPS);
            int trow = w * 32 + i * 16 + (lane >> 4) * 4 + r;
#pragma unroll
            for (int j = 0; j < 4; j++) {
                float o = aacc[i][j][r] * dinv;
                _Float16 hv = (_Float16)o;
                _Float16 lv = (_Float16)(o - (float)hv);
                Mh[(size_t)trow * 2048 + j * 16 + (lane & 15)]        = f16bits(hv);
                Mh[(size_t)trow * 2048 + 1024 + j * 16 + (lane & 15)] = f16bits(lv);
            }
        }
    }
}

// ---------------------------------------------------------------------------
extern "C" void kernel_launch(void* const* d_in, const int* in_sizes, int n_in,
                              void* d_out, int out_size, void* d_ws, size_t ws_size,
                              hipStream_t stream)
{
    (void)in_sizes; (void)n_in; (void)out_size; (void)ws_size;
    const float* x    = (const float*)d_in[0];
    const float* Wq   = (const float*)d_in[1];
    const float* Wk   = (const float*)d_in[2];
    const float* Wv   = (const float*)d_in[3];
    const float* Wo   = (const float*)d_in[4];
    const float* bo   = (const float*)d_in[5];
    const float* proj = (const float*)d_in[6];
    float* out = (float*)d_out;

    float* ws  = (float*)d_ws;
    float* Qs  = ws;                          // 8388608 floats
    float* Ks  = Qs + 8388608ull;             // 8388608
    float* Vb  = Ks + 8388608ull;             // 8388608
    float* phi = Vb + 8388608ull;             // 33554432 (phiK only)
    float* KVp = phi + 33554432ull;           // 8*32*256*68 = 4456448

    // aliases (lifetime-disjoint with their hosts):
    unsigned short* x_hl  = (unsigned short*)phi;  // dead once favor writes phi
    unsigned short* wqkv  = (unsigned short*)KVp;  // dead before kv_partial writes
    unsigned short* wo_h  = (unsigned short*)Qs;   // written after Qs is dead
    unsigned short* m_hl  = (unsigned short*)Ks;   // written after Ks is dead
    unsigned short* KVt16 = (unsigned short*)phi;  // written after phiK is dead

    dim3 gthr(256);

    split_w3h<<<dim3(3072), gthr, 0, stream>>>(Wq, Wk, Wv, wqkv);
    split_hl <<<dim3(8192), gthr, 0, stream>>>(x, x_hl);
    // QKV projection: 768 blocks, 2 blocks/CU
    gemm_hl<<<dim3(12, 64), gthr, 65536, stream>>>(
        x_hl, wqkv, wqkv + 1048576, wqkv + 2097152,
        Qs, Ks, Vb, nullptr, 0.125f, 0.125f, 1.0f);

    favor_mfma<<<dim3(32, 32), gthr, 0, stream>>>(Ks, proj, phi);      // phiK (clobbers x_hl, dead)
    kv_partial<<<dim3(32, 32), gthr, 0, stream>>>(phi, Vb, KVp);       // clobbers wqkv (dead)
    kv_reduce <<<dim3(2176),   gthr, 0, stream>>>(KVp, KVt16);         // KVt16 over dead phiK
    favor_attn<<<dim3(32, 32), gthr, 72192, stream>>>(Qs, proj, KVt16, m_hl);  // Qs dead after
    split_w3h <<<dim3(1024),   gthr, 0, stream>>>(Wo, Wo, Wo, wo_h);   // into Qs region

    // out projection: 256 blocks
    gemm_hl<<<dim3(4, 64), gthr, 65536, stream>>>(
        m_hl, wo_h, wo_h, wo_h, out, out, out, bo, 1.0f, 1.0f, 1.0f);
}

// Round 3
// 371.070 us; speedup vs baseline: 1.0601x; 1.0601x over previous
//
#include <hip/hip_runtime.h>
#include <hip/hip_bf16.h>
#include <math.h>

// Problem constants (FavorPlusAttention): B=2, T=4096, d=1024, h=16, dk=64, m=256
#define BB 2
#define TT 4096
#define DD 1024
#define NH 16
#define DK 64
#define MM 256
#define BT (BB*TT)        // 8192 rows
#define FEPS 1e-6f

typedef _Float16 f16x8 __attribute__((ext_vector_type(8)));
using f32x4 = __attribute__((ext_vector_type(4))) float;

#define GL2LDS16(g, l) __builtin_amdgcn_global_load_lds( \
    (const __attribute__((address_space(1))) void*)(g), \
    (__attribute__((address_space(3))) void*)(l), 16, 0, 0)

static __device__ __forceinline__ unsigned short f16bits(_Float16 v) {
    union { _Float16 f; unsigned short u; } c; c.f = v; return c.u;
}

// ---------------------------------------------------------------------------
// packed hi/lo split: src [rows][1024] f32 -> dst [rows][1024] u32 (hi|lo<<16)
// ---------------------------------------------------------------------------
__global__ __launch_bounds__(256) void split_pk(const float* __restrict__ src,
                                                unsigned int* __restrict__ dst)
{
    const int rr = blockIdx.x;
    const int c = threadIdx.x * 4;
    float4 v = *(const float4*)(src + (size_t)rr * 1024 + c);
    float f[4] = {v.x, v.y, v.z, v.w};
    uint4 o;
    unsigned int* op = (unsigned int*)&o;
#pragma unroll
    for (int i = 0; i < 4; i++) {
        _Float16 h = (_Float16)f[i];
        _Float16 l = (_Float16)(f[i] - (float)h);
        op[i] = (unsigned int)f16bits(h) | ((unsigned int)f16bits(l) << 16);
    }
    *(uint4*)(dst + (size_t)rr * 1024 + c) = o;
}

// hi-only fp16 weight cast: 3 weights -> [3][1024][1024] f16 (B-operand).
__global__ __launch_bounds__(256) void split_w3h(const float* __restrict__ W0,
                                                 const float* __restrict__ W1,
                                                 const float* __restrict__ W2,
                                                 unsigned short* __restrict__ dst)
{
    const int rr = blockIdx.x;           // 0..3071
    const int wi = rr >> 10, r2 = rr & 1023;
    const float* W = (wi == 0) ? W0 : (wi == 1) ? W1 : W2;
    const int c = threadIdx.x * 4;
    float4 v = *(const float4*)(W + (size_t)r2 * 1024 + c);
    float f[4] = {v.x, v.y, v.z, v.w};
    union { _Float16 h[4]; uint2 u; } hv;
#pragma unroll
    for (int i = 0; i < 4; i++) hv.h[i] = (_Float16)f[i];
    *(uint2*)(dst + (size_t)rr * 1024 + c) = hv.u;
}

// ---------------------------------------------------------------------------
// gemm_pk: packed-hi/lo split-fp16 GEMM. C = scale*((A_hi+A_lo)@B_hi^T)(+bias)
// A: [8192][1024] u32 packed (hi|lo<<16). B: [1024][1024] f16 hi. K=1024,
// BK=32 real-k, 32 K-tiles. BM=128, BN=128, 4 waves (2Mx2N), wave tile 64x64
// (acc[4][4] f32x4 = 64 AGPR).
// hi/lo fusion INSIDE the MFMA k-reduction: A frag = interleaved [h,l,h,l..]
// read directly as f16x8; B frag = pairwise-DUPLICATED values (slot j holds
// B[j/2]) built in-register via v_perm from a ds_read_b64. Then
// sum_j A_j*B_j = sum_k (h_k+l_k)*B_k.
// LDS 48 KB (3 blocks/CU = 144 KB): A buf 2x16KB [128 rows][128B], sigma=r&7
// XOR swizzle (free 2-way); B buf 2x8KB [128 rows][64B], sigma=(r>>1)&3.
// Staging via gl2lds w/ pre-swizzled source: A 8-lane/128B contiguous
// segments, B 4-lane/64B (R2 post-mortem: staging coalescing is first-class).
// Schedule (verified 2-phase counted-vmcnt skeleton):
//  P0: stage A(t+1)[4]; read af[4](b128 ks0) + rb[4][2](b64, ALL B); bar;
//      lgkm0; SB; dup-perm ks0; prio1; 16 MFMA ks0; prio0; bar.
//  P1: stage B(t+2)[2]; read af2[4](ks1); vmcnt(2); bar; lgkm0; SB;
//      dup-perm ks1; prio1; 16 MFMA ks1; prio0; bar.
// Ledger: enter t with B(t+1)[2] outstanding; P0 +A(t+1)[4]; P1 +B(t+2)[2];
// vmcnt(2) -> exactly tile t+1 landed. All B reads in P0 so stB (same-buf
// write, (t+2)&1 == t&1) is safe after P0's end barrier.
// ---------------------------------------------------------------------------
__global__ __launch_bounds__(256, 3) void gemm_pk(
    const unsigned int* __restrict__ A,
    const unsigned short* __restrict__ B0, const unsigned short* __restrict__ B1,
    const unsigned short* __restrict__ B2,
    float* __restrict__ C0, float* __restrict__ C1, float* __restrict__ C2,
    const float* __restrict__ bias,
    float sc0, float sc1, float sc2)
{
    extern __shared__ char smem[];   // 49152: A0 @0, A1 @16384, B0 @32768, B1 @40960

    const int which = blockIdx.x >> 3;
    const int col0 = (blockIdx.x & 7) * 128;
    const int row0 = blockIdx.y * 128;
    const unsigned short* Bp = (which == 0) ? B0 : (which == 1) ? B1 : B2;
    float* Cp = (which == 0) ? C0 : (which == 1) ? C1 : C2;
    const float scl = (which == 0) ? sc0 : (which == 1) ? sc1 : sc2;

    const int tid = threadIdx.x;             // 0..255
    const int w = tid >> 6, lane = tid & 63;
    const int wm = w >> 1, wn = w & 1;       // 2M x 2N wave grid
    const int r = lane & 15, q = lane >> 4;

    // ---- staging precompute ----
    // A: 1024 slots (128 rows x 8 chunks of 16B); slot s = tid + i*256;
    // row = s>>3, c = s&7, src chunk = c ^ (row&7)  [pre-swizzled source]
    const unsigned int* aP[4];
    int dstA[4];
#pragma unroll
    for (int i = 0; i < 4; i++) {
        int s = tid + i * 256;
        int row = s >> 3, c = s & 7;
        aP[i] = A + (size_t)(row0 + row) * 1024 + (c ^ (row & 7)) * 4;
        dstA[i] = (i * 256 + w * 64) * 16;
    }
    // B: 512 slots (128 rows x 4 chunks of 16B); src chunk = c ^ ((row>>1)&3)
    const unsigned short* bP[2];
    int dstB[2];
#pragma unroll
    for (int i = 0; i < 2; i++) {
        int s = tid + i * 256;
        int row = s >> 2, c = s & 3;
        bP[i] = Bp + (size_t)(col0 + row) * 1024 + (c ^ ((row >> 1) & 3)) * 8;
        dstB[i] = (i * 256 + w * 64) * 16;
    }

    auto stA = [&](int buf, int kt) {
        char* base = smem + buf * 16384;
        const int ko = kt * 32;              // u32 units
#pragma unroll
        for (int i = 0; i < 4; i++) GL2LDS16(aP[i] + ko, base + dstA[i]);
    };
    auto stB = [&](int buf, int kt) {
        char* base = smem + 32768 + buf * 8192;
        const int ko = kt * 32;              // short units
#pragma unroll
        for (int i = 0; i < 2; i++) GL2LDS16(bP[i] + ko, base + dstB[i]);
    };

    // ---- frag read offsets ----
    // A frag (mf, ks): byte = (wm*64 + mf*16 + r)*128 + ((ks*4+q)^(r&7))*16
    const int aRow = (wm * 64 + r) * 128;
    const int kxA0 = ((0 + q) ^ (r & 7)) * 16;
    const int kxA1 = ((4 + q) ^ (r & 7)) * 16;
    // B frag (nf, ks): b64 of 4 real-k; 8B slot w8 = ks*4+q stored at 16B pos
    // (w8>>1)^((r>>1)&3), half w8&1.
    const int bRow = (wn * 64 + r) * 64;
    const int sB = (r >> 1) & 3;
    const int bo0 = (((q >> 1) ^ sB) * 16) + (q & 1) * 8;          // ks=0
    const int bo1 = (((2 + (q >> 1)) ^ sB) * 16) + (q & 1) * 8;    // ks=1

    auto dup = [](uint2 v) -> f16x8 {        // pairwise-duplicate 4 f16 -> f16x8
        union { unsigned int u[4]; f16x8 f; } o;
        o.u[0] = __builtin_amdgcn_perm(v.x, v.x, 0x01000100u);
        o.u[1] = __builtin_amdgcn_perm(v.x, v.x, 0x03020302u);
        o.u[2] = __builtin_amdgcn_perm(v.y, v.y, 0x01000100u);
        o.u[3] = __builtin_amdgcn_perm(v.y, v.y, 0x03020302u);
        return o.f;
    };

    f32x4 acc[4][4];
#pragma unroll
    for (int i = 0; i < 4; i++)
#pragma unroll
        for (int j = 0; j < 4; j++) acc[i][j] = (f32x4){0.f, 0.f, 0.f, 0.f};

    // ---- prologue: queue = B(0)[2], A(0)[4], B(1)[2]; vmcnt(2) -> tile0 in
    stB(0, 0);
    stA(0, 0);
    stB(1, 1);
    asm volatile("s_waitcnt vmcnt(2)" ::: "memory");
    __builtin_amdgcn_s_barrier();

#pragma unroll 2
    for (int t = 0; t < 32; ++t) {
        const int buf = t & 1;
        const int ab = buf * 16384;
        const int bb = 32768 + buf * 8192;
        f16x8 af[4];
        uint2 rb[4][2];
        // ============ phase 0: stage A(t+1); read af(ks0) + ALL B; MFMA ks0
        stA(buf ^ 1, (t + 1 < 32) ? t + 1 : 0);
#pragma unroll
        for (int mf = 0; mf < 4; ++mf)
            af[mf] = *(const f16x8*)(smem + ab + aRow + mf * 2048 + kxA0);
#pragma unroll
        for (int nf = 0; nf < 4; ++nf) {
            rb[nf][0] = *(const uint2*)(smem + bb + bRow + nf * 1024 + bo0);
            rb[nf][1] = *(const uint2*)(smem + bb + bRow + nf * 1024 + bo1);
        }
        __builtin_amdgcn_s_barrier();
        asm volatile("s_waitcnt lgkmcnt(0)" ::: "memory");
        __builtin_amdgcn_sched_barrier(0);
        {
            f16x8 bfr[4];
#pragma unroll
            for (int nf = 0; nf < 4; ++nf) bfr[nf] = dup(rb[nf][0]);
            __builtin_amdgcn_s_setprio(1);
#pragma unroll
            for (int mf = 0; mf < 4; ++mf)
#pragma unroll
                for (int nf = 0; nf < 4; ++nf)
                    acc[mf][nf] = __builtin_amdgcn_mfma_f32_16x16x32_f16(
                        af[mf], bfr[nf], acc[mf][nf], 0, 0, 0);
            __builtin_amdgcn_s_setprio(0);
        }
        __builtin_amdgcn_s_barrier();
        // ============ phase 1: stage B(t+2); read af(ks1); vmcnt; MFMA ks1
        stB(buf, (t + 2 < 32) ? t + 2 : 0);
#pragma unroll
        for (int mf = 0; mf < 4; ++mf)
            af[mf] = *(const f16x8*)(smem + ab + aRow + mf * 2048 + kxA1);
        asm volatile("s_waitcnt vmcnt(2)" ::: "memory");
        __builtin_amdgcn_s_barrier();
        asm volatile("s_waitcnt lgkmcnt(0)" ::: "memory");
        __builtin_amdgcn_sched_barrier(0);
        {
            f16x8 bfr[4];
#pragma unroll
            for (int nf = 0; nf < 4; ++nf) bfr[nf] = dup(rb[nf][1]);
            __builtin_amdgcn_s_setprio(1);
#pragma unroll
            for (int mf = 0; mf < 4; ++mf)
#pragma unroll
                for (int nf = 0; nf < 4; ++nf)
                    acc[mf][nf] = __builtin_amdgcn_mfma_f32_16x16x32_f16(
                        af[mf], bfr[nf], acc[mf][nf], 0, 0, 0);
            __builtin_amdgcn_s_setprio(0);
        }
        __builtin_amdgcn_s_barrier();
    }
    asm volatile("s_waitcnt vmcnt(0)" ::: "memory");   // drain tail junk loads

    // ---- epilogue: C/D layout col = lane&15, row = (lane>>4)*4 + reg  [m89]
    float bv[4];
#pragma unroll
    for (int nf = 0; nf < 4; ++nf) {
        int gcol = col0 + wn * 64 + nf * 16 + r;
        bv[nf] = bias ? bias[gcol] : 0.f;
    }
#pragma unroll
    for (int mf = 0; mf < 4; ++mf) {
        const int grow = row0 + wm * 64 + mf * 16 + q * 4;
#pragma unroll
        for (int rr = 0; rr < 4; ++rr) {
            float* Crow = Cp + (size_t)(grow + rr) * 1024;
#pragma unroll
            for (int nf = 0; nf < 4; ++nf) {
                int gcol = col0 + wn * 64 + nf * 16 + r;
                Crow[gcol] = acc[mf][nf][rr] * scl + bv[nf];
            }
        }
    }
}

// ---------------------------------------------------------------------------
// FAVOR+ features via MFMA (phiK only): per block one bh, [128 t x 256 m].
// Unchanged (verified).
// ---------------------------------------------------------------------------
__global__ __launch_bounds__(256) void favor_mfma(const float* __restrict__ X,
                                                  const float* __restrict__ proj,
                                                  float* __restrict__ phi)
{
    const int bh = blockIdx.y;
    const int b = bh >> 4, h = bh & 15;
    const int t0 = blockIdx.x * 128;
    const int tid = threadIdx.x;
    const int w = tid >> 6, lane = tid & 63;

    __shared__ unsigned short Aq[128 * 136];   // [t][k'], hi 0..63, lo 64..127
    __shared__ unsigned short Bs[256 * 72];    // [m][k] hi only
    __shared__ float xns[128];

    const float* Xb = X + ((size_t)b * TT + t0) * DD + h * DK;
    const float* Pj = proj + (size_t)h * MM * DK;

#pragma unroll
    for (int i = 0; i < 8; i++) {
        int s = tid + i * 256;
        int rr = s >> 4, qq = (s & 15) * 4;
        float4 v = *(const float4*)(Xb + (size_t)rr * DD + qq);
        float f[4] = {v.x, v.y, v.z, v.w};
        union { _Float16 h[4]; uint2 u; } hv, lv;
#pragma unroll
        for (int e = 0; e < 4; e++) {
            hv.h[e] = (_Float16)f[e];
            lv.h[e] = (_Float16)(f[e] - (float)hv.h[e]);
        }
        *(uint2*)&Aq[rr * 136 + qq]      = hv.u;
        *(uint2*)&Aq[rr * 136 + 64 + qq] = lv.u;
    }
#pragma unroll
    for (int i = 0; i < 16; i++) {
        int s = tid + i * 256;
        int rr = s >> 4, qq = (s & 15) * 4;
        float4 v = *(const float4*)(Pj + (size_t)rr * DK + qq);
        float f[4] = {v.x, v.y, v.z, v.w};
        union { _Float16 h[4]; uint2 u; } hv;
#pragma unroll
        for (int e = 0; e < 4; e++) hv.h[e] = (_Float16)f[e];
        *(uint2*)&Bs[rr * 72 + qq] = hv.u;
    }
    __syncthreads();

    if (tid < 128) {
        const unsigned short* ar = &Aq[tid * 136];
        float s = 0.f;
#pragma unroll 8
        for (int k = 0; k < 64; k++) {
            float qv = (float)(*(const _Float16*)&ar[k])
                     + (float)(*(const _Float16*)&ar[64 + k]);
            s += qv * qv;
        }
        xns[tid] = s;
    }

    f32x4 acc[2][16];
#pragma unroll
    for (int i = 0; i < 2; i++)
#pragma unroll
        for (int j = 0; j < 16; j++) acc[i][j] = (f32x4){0.f, 0.f, 0.f, 0.f};

    const int arow0 = (w * 32 + (lane & 15)) * 136 + (lane >> 4) * 8;
    const int brow0 = (lane & 15) * 72 + (lane >> 4) * 8;
#pragma unroll
    for (int ks = 0; ks < 4; ks++) {
        f16x8 a0 = *(const f16x8*)&Aq[arow0 + ks * 32];
        f16x8 a1 = *(const f16x8*)&Aq[arow0 + 16 * 136 + ks * 32];
        const int bko = (ks & 1) * 32;
#pragma unroll
        for (int j = 0; j < 16; j++) {
            f16x8 bf = *(const f16x8*)&Bs[brow0 + j * 16 * 72 + bko];
            acc[0][j] = __builtin_amdgcn_mfma_f32_16x16x32_f16(a0, bf, acc[0][j], 0, 0, 0);
            acc[1][j] = __builtin_amdgcn_mfma_f32_16x16x32_f16(a1, bf, acc[1][j], 0, 0, 0);
        }
    }
    __syncthreads();

    float* outp = phi + ((size_t)bh * TT + t0) * MM;
#pragma unroll
    for (int i = 0; i < 2; i++) {
#pragma unroll
        for (int rr = 0; rr < 4; rr++) {
            float mx = acc[i][0][rr];
#pragma unroll
            for (int j = 1; j < 16; j++) mx = fmaxf(mx, acc[i][j][rr]);
            mx = fmaxf(mx, __shfl_xor(mx, 1, 64));
            mx = fmaxf(mx, __shfl_xor(mx, 2, 64));
            mx = fmaxf(mx, __shfl_xor(mx, 4, 64));
            mx = fmaxf(mx, __shfl_xor(mx, 8, 64));
            const int row = w * 32 + i * 16 + (lane >> 4) * 4 + rr;
            const float base = -mx - 0.5f * xns[row];
            float* orow = outp + (size_t)row * MM + (lane & 15);
#pragma unroll
            for (int j = 0; j < 16; j++)
                orow[j * 16] = (__expf(acc[i][j][rr] + base) + FEPS) * 0.0625f;
        }
    }
}

// ---------------------------------------------------------------------------
// KV partial tiled GEMM: per block [64 m x 64 dk] over a 512-long t-chunk.
// (unchanged)
// ---------------------------------------------------------------------------
__global__ __launch_bounds__(256) void kv_partial(const float* __restrict__ phiK,
                                                  const float* __restrict__ V,
                                                  float* __restrict__ KVp)
{
    const int bh = blockIdx.y;
    const int b = bh >> 4, h = bh & 15;
    const int mt = blockIdx.x & 3;          // m-tile (64 wide)
    const int split = blockIdx.x >> 2;      // 0..7, 512 t each
    const int m0 = mt * 64;
    const int tid = threadIdx.x;
    const int tx = tid & 15;    // dk, 4 each
    const int ty = tid >> 4;    // m, 4 each

    __shared__ float Ps[32][68];
    __shared__ float Vs[32][68];

    float acc[4][4];
#pragma unroll
    for (int i = 0; i < 4; i++)
#pragma unroll
        for (int j = 0; j < 4; j++) acc[i][j] = 0.f;
    float ks0 = 0.f, ks1 = 0.f, ks2 = 0.f, ks3 = 0.f;

    const size_t pbase = (size_t)bh * TT * MM + m0;
    const size_t vbase = (size_t)b * TT * DD + h * DK;

    const int lt = tid >> 3;
    const int lc = (tid & 7) * 8;

    const int tend = split * 512 + 512;
    for (int t0 = split * 512; t0 < tend; t0 += 32) {
        const float* prow = phiK + pbase + (size_t)(t0 + lt) * MM + lc;
        const float* vrow = V + vbase + (size_t)(t0 + lt) * DD + lc;
        float4 p0 = *(const float4*)(prow);
        float4 p1 = *(const float4*)(prow + 4);
        float4 v0 = *(const float4*)(vrow);
        float4 v1 = *(const float4*)(vrow + 4);
        *(float4*)&Ps[lt][lc]     = p0;
        *(float4*)&Ps[lt][lc + 4] = p1;
        *(float4*)&Vs[lt][lc]     = v0;
        *(float4*)&Vs[lt][lc + 4] = v1;
        __syncthreads();
#pragma unroll
        for (int k = 0; k < 32; k++) {
            float4 a4 = *(const float4*)&Ps[k][ty * 4];
            float4 b4 = *(const float4*)&Vs[k][tx * 4];
            ks0 += a4.x; ks1 += a4.y; ks2 += a4.z; ks3 += a4.w;
            acc[0][0] += a4.x * b4.x; acc[0][1] += a4.x * b4.y;
            acc[0][2] += a4.x * b4.z; acc[0][3] += a4.x * b4.w;
            acc[1][0] += a4.y * b4.x; acc[1][1] += a4.y * b4.y;
            acc[1][2] += a4.y * b4.z; acc[1][3] += a4.y * b4.w;
            acc[2][0] += a4.z * b4.x; acc[2][1] += a4.z * b4.y;
            acc[2][2] += a4.z * b4.z; acc[2][3] += a4.z * b4.w;
            acc[3][0] += a4.w * b4.x; acc[3][1] += a4.w * b4.y;
            acc[3][2] += a4.w * b4.z; acc[3][3] += a4.w * b4.w;
        }
        __syncthreads();
    }

    float ksv[4] = {ks0, ks1, ks2, ks3};
    float* o = KVp + (((size_t)split * 32 + bh) * MM + m0) * 68;
#pragma unroll
    for (int i = 0; i < 4; i++) {
        float* orow = o + (size_t)(ty * 4 + i) * 68 + tx * 4;
        orow[0] = acc[i][0]; orow[1] = acc[i][1];
        orow[2] = acc[i][2]; orow[3] = acc[i][3];
        if (tx == 0) o[(size_t)(ty * 4 + i) * 68 + 64] = ksv[i];
    }
}

// ---------------------------------------------------------------------------
// kv_reduce v2: sum 8 split partials and emit KV^T directly as fp16 hi/lo
// planes: KVt16[bh][plane(2)][c(68)][m(256)], c: 0..63 = dk, 64 = Ksum.
// ---------------------------------------------------------------------------
__global__ __launch_bounds__(256) void kv_reduce(const float* __restrict__ KVp,
                                                 unsigned short* __restrict__ KVt16)
{
    int idx = blockIdx.x * 256 + threadIdx.x;   // 32*256*68 = 557056 exact
    float s = 0.f;
    for (int sp = 0; sp < 8; sp++) s += KVp[(size_t)sp * 32 * MM * 68 + idx];
    int bh = idx / 17408;
    int rm = idx - bh * 17408;
    int m = rm / 68;
    int c = rm - m * 68;
    _Float16 hv = (_Float16)0.f, lv = (_Float16)0.f;
    if (c <= 64) {
        hv = (_Float16)s;
        lv = (_Float16)(s - (float)hv);
    }
    KVt16[((size_t)(bh * 2 + 0) * 68 + c) * 256 + m] = f16bits(hv);
    KVt16[((size_t)(bh * 2 + 1) * 68 + c) * 256 + m] = f16bits(lv);
}

// ---------------------------------------------------------------------------
// FUSED favor(Q) + attn_out: per block one bh, 128 t rows.
// Epilogue now writes merged output PACKED u32 (hi|lo<<16) [8192][1024] for
// the packed out-projection GEMM. Otherwise unchanged (verified).
// ---------------------------------------------------------------------------
__global__ __launch_bounds__(256, 2) void favor_attn(
    const float* __restrict__ X,
    const float* __restrict__ proj,
    const unsigned short* __restrict__ KVt16,
    unsigned int* __restrict__ mout)
{
    extern __shared__ char smem[];
    unsigned short* Xq = (unsigned short*)smem;             // [128][136]
    unsigned short* Pp = (unsigned short*)(smem + 34816);   // [256][72]
    float* xns         = (float*)(smem + 71680);            // [128]
    unsigned short* Aq = Xq;                                // phase B alias
    unsigned short* Bt = Pp;                                // [80][136]

    const int bh = blockIdx.y;
    const int b = bh >> 4, h = bh & 15;
    const int t0 = blockIdx.x * 128;
    const int tid = threadIdx.x;
    const int w = tid >> 6, lane = tid & 63;

    const float* Xb = X + ((size_t)b * TT + t0) * DD + h * DK;
    const float* Pj = proj + (size_t)h * MM * DK;

    // ---- phase A: stage X (hi/lo) + proj (hi) ----
#pragma unroll
    for (int i = 0; i < 8; i++) {
        int s = tid + i * 256;
        int rr = s >> 4, qq = (s & 15) * 4;
        float4 v = *(const float4*)(Xb + (size_t)rr * DD + qq);
        float f[4] = {v.x, v.y, v.z, v.w};
        union { _Float16 h[4]; uint2 u; } hv, lv;
#pragma unroll
        for (int e = 0; e < 4; e++) {
            hv.h[e] = (_Float16)f[e];
            lv.h[e] = (_Float16)(f[e] - (float)hv.h[e]);
        }
        *(uint2*)&Xq[rr * 136 + qq]      = hv.u;
        *(uint2*)&Xq[rr * 136 + 64 + qq] = lv.u;
    }
#pragma unroll
    for (int i = 0; i < 16; i++) {
        int s = tid + i * 256;
        int rr = s >> 4, qq = (s & 15) * 4;
        float4 v = *(const float4*)(Pj + (size_t)rr * DK + qq);
        float f[4] = {v.x, v.y, v.z, v.w};
        union { _Float16 h[4]; uint2 u; } hv;
#pragma unroll
        for (int e = 0; e < 4; e++) hv.h[e] = (_Float16)f[e];
        *(uint2*)&Pp[rr * 72 + qq] = hv.u;
    }
    __syncthreads();

    if (tid < 128) {
        const unsigned short* ar = &Xq[tid * 136];
        float s = 0.f;
#pragma unroll 8
        for (int k = 0; k < 64; k++) {
            float qv = (float)(*(const _Float16*)&ar[k])
                     + (float)(*(const _Float16*)&ar[64 + k]);
            s += qv * qv;
        }
        xns[tid] = s;
    }

    f32x4 facc[2][16];
#pragma unroll
    for (int i = 0; i < 2; i++)
#pragma unroll
        for (int j = 0; j < 16; j++) facc[i][j] = (f32x4){0.f, 0.f, 0.f, 0.f};

    const int arow0 = (w * 32 + (lane & 15)) * 136 + (lane >> 4) * 8;
    const int brow0 = (lane & 15) * 72 + (lane >> 4) * 8;
#pragma unroll
    for (int ks = 0; ks < 4; ks++) {
        f16x8 a0 = *(const f16x8*)&Xq[arow0 + ks * 32];
        f16x8 a1 = *(const f16x8*)&Xq[arow0 + 16 * 136 + ks * 32];
        const int bko = (ks & 1) * 32;
#pragma unroll
        for (int j = 0; j < 16; j++) {
            f16x8 bf = *(const f16x8*)&Pp[brow0 + j * 16 * 72 + bko];
            facc[0][j] = __builtin_amdgcn_mfma_f32_16x16x32_f16(a0, bf, facc[0][j], 0, 0, 0);
            facc[1][j] = __builtin_amdgcn_mfma_f32_16x16x32_f16(a1, bf, facc[1][j], 0, 0, 0);
        }
    }
    __syncthreads();   // phase A LDS reads done; xns visible

    // rowmax -> base per (i, r)
    float base[2][4];
#pragma unroll
    for (int i = 0; i < 2; i++) {
#pragma unroll
        for (int rr = 0; rr < 4; rr++) {
            float mx = facc[i][0][rr];
#pragma unroll
            for (int j = 1; j < 16; j++) mx = fmaxf(mx, facc[i][j][rr]);
            mx = fmaxf(mx, __shfl_xor(mx, 1, 64));
            mx = fmaxf(mx, __shfl_xor(mx, 2, 64));
            mx = fmaxf(mx, __shfl_xor(mx, 4, 64));
            mx = fmaxf(mx, __shfl_xor(mx, 8, 64));
            const int row = w * 32 + i * 16 + (lane >> 4) * 4 + rr;
            base[i][rr] = -mx - 0.5f * xns[row];
        }
    }

    // ---- phase B: chunked phi->Aq + KV^T->Bt + 3-seg MFMA ----
    f32x4 aacc[2][5];
#pragma unroll
    for (int i = 0; i < 2; i++)
#pragma unroll
        for (int j = 0; j < 5; j++) aacc[i][j] = (f32x4){0.f, 0.f, 0.f, 0.f};

    const int aFr = (w * 32 + (lane & 15)) * 136 + (lane >> 4) * 8;
    const int bFr = (lane & 15) * 136 + (lane >> 4) * 8;

#pragma unroll
    for (int c = 0; c < 4; c++) {
        // write phi chunk (hi|lo) to Aq in A-layout [t][mc]
#pragma unroll
        for (int i = 0; i < 2; i++) {
#pragma unroll
            for (int jj = 0; jj < 4; jj++) {
#pragma unroll
                for (int rr = 0; rr < 4; rr++) {
                    float ph = (__expf(facc[i][c * 4 + jj][rr] + base[i][rr]) + FEPS) * 0.0625f;
                    _Float16 hv = (_Float16)ph;
                    _Float16 lv = (_Float16)(ph - (float)hv);
                    int row = w * 32 + i * 16 + (lane >> 4) * 4 + rr;
                    int mc = jj * 16 + (lane & 15);
                    Aq[row * 136 + mc]      = f16bits(hv);
                    Aq[row * 136 + 64 + mc] = f16bits(lv);
                }
            }
        }
        // stage Bt chunk: rows 0..67 from KVt16, 68..79 zero
#pragma unroll
        for (int i = 0; i < 10; i++) {
            int s = tid + i * 256;           // 2560 = 2 planes * 80 rows * 16 quads
            int p = (s >= 1280) ? 1 : 0;
            int s2 = s - p * 1280;
            int rr = s2 >> 4, qq = (s2 & 15) * 4;
            uint2 v = make_uint2(0u, 0u);
            if (rr < 68)
                v = *(const uint2*)(KVt16 + ((size_t)(bh * 2 + p) * 68 + rr) * 256 + c * 64 + qq);
            *(uint2*)&Bt[rr * 136 + p * 64 + qq] = v;
        }
        __syncthreads();
#pragma unroll
        for (int ks = 0; ks < 2; ks++) {
            f16x8 ah0 = *(const f16x8*)&Aq[aFr + ks * 32];
            f16x8 ah1 = *(const f16x8*)&Aq[aFr + 16 * 136 + ks * 32];
            f16x8 al0 = *(const f16x8*)&Aq[aFr + 64 + ks * 32];
            f16x8 al1 = *(const f16x8*)&Aq[aFr + 16 * 136 + 64 + ks * 32];
#pragma unroll
            for (int j = 0; j < 5; j++) {
                f16x8 bh_ = *(const f16x8*)&Bt[bFr + j * 16 * 136 + ks * 32];
                f16x8 bl_ = *(const f16x8*)&Bt[bFr + j * 16 * 136 + 64 + ks * 32];
                aacc[0][j] = __builtin_amdgcn_mfma_f32_16x16x32_f16(ah0, bl_, aacc[0][j], 0, 0, 0);
                aacc[0][j] = __builtin_amdgcn_mfma_f32_16x16x32_f16(al0, bh_, aacc[0][j], 0, 0, 0);
                aacc[0][j] = __builtin_amdgcn_mfma_f32_16x16x32_f16(ah0, bh_, aacc[0][j], 0, 0, 0);
                aacc[1][j] = __builtin_amdgcn_mfma_f32_16x16x32_f16(ah1, bl_, aacc[1][j], 0, 0, 0);
                aacc[1][j] = __builtin_amdgcn_mfma_f32_16x16x32_f16(al1, bh_, aacc[1][j], 0, 0, 0);
                aacc[1][j] = __builtin_amdgcn_mfma_f32_16x16x32_f16(ah1, bh_, aacc[1][j], 0, 0, 0);
            }
        }
        __syncthreads();
    }

    // ---- epilogue: out = num/(den+eps), write merged PACKED u32 hi|lo ----
    unsigned int* Mp = mout + ((size_t)b * TT + t0) * 1024 + h * DK;
#pragma unroll
    for (int i = 0; i < 2; i++) {
#pragma unroll
        for (int rr = 0; rr < 4; rr++) {
            float den = aacc[i][4][rr];                // col 64 lives at lane&15==0
            den = __shfl(den, lane & 48, 64);          // broadcast to the 16-lane group
            float dinv = 1.f / (den + FEPS);
            int trow = w * 32 + i * 16 + (lane >> 4) * 4 + rr;
#pragma unroll
            for (int j = 0; j < 4; j++) {
                float o = aacc[i][j][rr] * dinv;
                _Float16 hv = (_Float16)o;
                _Float16 lv = (_Float16)(o - (float)hv);
                Mp[(size_t)trow * 1024 + j * 16 + (lane & 15)] =
                    (unsigned int)f16bits(hv) | ((unsigned int)f16bits(lv) << 16);
            }
        }
    }
}

// ---------------------------------------------------------------------------
extern "C" void kernel_launch(void* const* d_in, const int* in_sizes, int n_in,
                              void* d_out, int out_size, void* d_ws, size_t ws_size,
                              hipStream_t stream)
{
    (void)in_sizes; (void)n_in; (void)out_size; (void)ws_size;
    const float* x    = (const float*)d_in[0];
    const float* Wq   = (const float*)d_in[1];
    const float* Wk   = (const float*)d_in[2];
    const float* Wv   = (const float*)d_in[3];
    const float* Wo   = (const float*)d_in[4];
    const float* bo   = (const float*)d_in[5];
    const float* proj = (const float*)d_in[6];
    float* out = (float*)d_out;

    float* ws  = (float*)d_ws;
    float* Qs  = ws;                          // 8388608 floats
    float* Ks  = Qs + 8388608ull;             // 8388608
    float* Vb  = Ks + 8388608ull;             // 8388608
    float* phi = Vb + 8388608ull;             // 33554432 (phiK only)
    float* KVp = phi + 33554432ull;           // 8*32*256*68 = 4456448

    // aliases (lifetime-disjoint with their hosts):
    unsigned int*   x_pk  = (unsigned int*)phi;    // dead once favor writes phi
    unsigned short* wqkv  = (unsigned short*)KVp;  // dead before kv_partial writes
    unsigned short* wo_h  = (unsigned short*)Qs;   // written after Qs is dead
    unsigned int*   m_pk  = (unsigned int*)Ks;     // written after Ks is dead
    unsigned short* KVt16 = (unsigned short*)phi;  // written after phiK is dead

    dim3 gthr(256);

    split_w3h<<<dim3(3072), gthr, 0, stream>>>(Wq, Wk, Wv, wqkv);
    split_pk <<<dim3(8192), gthr, 0, stream>>>(x, x_pk);
    // QKV projection: 1536 blocks, 3 blocks/CU, 2 full fills
    gemm_pk<<<dim3(24, 64), gthr, 49152, stream>>>(
        x_pk, wqkv, wqkv + 1048576, wqkv + 2097152,
        Qs, Ks, Vb, nullptr, 0.125f, 0.125f, 1.0f);

    favor_mfma<<<dim3(32, 32), gthr, 0, stream>>>(Ks, proj, phi);      // phiK (clobbers x_pk, dead)
    kv_partial<<<dim3(32, 32), gthr, 0, stream>>>(phi, Vb, KVp);       // clobbers wqkv (dead)
    kv_reduce <<<dim3(2176),   gthr, 0, stream>>>(KVp, KVt16);         // KVt16 over dead phiK
    favor_attn<<<dim3(32, 32), gthr, 72192, stream>>>(Qs, proj, KVt16, m_pk); // Qs dead after
    split_w3h <<<dim3(1024),   gthr, 0, stream>>>(Wo, Wo, Wo, wo_h);   // into Qs region

    // out projection: 512 blocks
    gemm_pk<<<dim3(8, 64), gthr, 49152, stream>>>(
        m_pk, wo_h, wo_h, wo_h, out, out, out, bo, 1.0f, 1.0f, 1.0f);
}